// Round 4
// baseline (165.745 us; speedup 1.0000x reference)
//
#include <hip/hip_runtime.h>

// Upscaler (W=8, R=4) == exact linear interpolation between block rows:
//   t = 4q + m:  t==0 -> 0;  t in 1..3 -> Z[0];  t>=4 -> (1-m/4)*Z[q-1] + (m/4)*Z[q]
// (row-norm denominator +1e-8 is below half-ulp of the sums -> exact; verified
//  round 1: absmax == 0.0)
//
// Shapes fixed by harness: B=4, N=2048, H=1024, S=8192, fp32.
// Structure: one block per (b, q-pair); 3 row-loads (cached, XCD-swizzled for
// L2 reuse), 8 row-stores (nontemporal: output is write-once, keep it out of L2).
//
// NOTE: __builtin_nontemporal_store needs a native clang vector type — HIP's
// float4 (HIP_vector_type struct) is rejected (round-3 compile error). Use
// ext_vector_type(4) float, same 16-byte layout.

typedef float f4 __attribute__((ext_vector_type(4)));

#define B_DIM 4
#define N_DIM 2048
#define H4    256                     // H=1024 floats -> 256 f4
#define S_DIM 8192
#define NBLK  (B_DIM * (N_DIM / 2))   // 4096 blocks, 2 q per block
#define NXCD  8
#define CHUNK (NBLK / NXCD)           // 512 (NBLK % NXCD == 0 -> bijective swizzle)

__global__ __launch_bounds__(256)
void Upscaler_33294586479031_kernel(const f4* __restrict__ Z,
                                    f4* __restrict__ out) {
    // XCD-aware swizzle: HW assigns blockIdx round-robin to XCDs; remap so each
    // XCD owns a contiguous run of q -> shared Z rows hit the same L2.
    const int bid = blockIdx.x;
    const int swz = (bid & (NXCD - 1)) * CHUNK + (bid >> 3);

    const int q2 = swz & (N_DIM / 2 - 1);   // q-pair index 0..1023
    const int b  = swz >> 10;               // batch 0..3
    const int h  = threadIdx.x;             // f4 lane 0..255
    const int q0 = q2 * 2;                  // first q of the pair

    const f4* zbase = Z + (size_t)b * (N_DIM * H4) + h;

    // Issue all loads up-front for MLP (clamp keeps q0==0 in bounds; result unused there).
    const int qm = (q0 > 0) ? (q0 - 1) : 0;
    const f4 zm = zbase[(size_t)qm * H4];
    const f4 z0 = zbase[(size_t)q0 * H4];
    const f4 z1 = zbase[(size_t)(q0 + 1) * H4];   // q0+1 <= N-1 always

    f4* ob = out + (size_t)b * (S_DIM * H4) + (size_t)(4 * q0) * H4 + h;

    if (q0 == 0) {
        // t=0 -> zeros; t=1..3 -> Z[b,0,:] exactly
        const f4 zero = (f4)(0.0f);
        __builtin_nontemporal_store(zero, &ob[0 * H4]);
        __builtin_nontemporal_store(z0,   &ob[1 * H4]);
        __builtin_nontemporal_store(z0,   &ob[2 * H4]);
        __builtin_nontemporal_store(z0,   &ob[3 * H4]);
    } else {
        #pragma unroll
        for (int m = 0; m < 4; ++m) {
            const float w1 = 0.25f * (float)m;
            const float w0 = 1.0f - w1;
            const f4 r = w0 * zm + w1 * z0;   // element-wise on native vectors
            __builtin_nontemporal_store(r, &ob[m * H4]);
        }
    }

    // Second group: t = 4*(q0+1) + m, blend(z0 -> z1)
    #pragma unroll
    for (int m = 0; m < 4; ++m) {
        const float w1 = 0.25f * (float)m;
        const float w0 = 1.0f - w1;
        const f4 r = w0 * z0 + w1 * z1;
        __builtin_nontemporal_store(r, &ob[(4 + m) * H4]);
    }
}

extern "C" void kernel_launch(void* const* d_in, const int* in_sizes, int n_in,
                              void* d_out, int out_size, void* d_ws, size_t ws_size,
                              hipStream_t stream) {
    const f4* Z = (const f4*)d_in[0];
    f4* out     = (f4*)d_out;

    Upscaler_33294586479031_kernel<<<NBLK, 256, 0, stream>>>(Z, out);
}

// Round 5
// 157.318 us; speedup vs baseline: 1.0536x; 1.0536x over previous
//
#include <hip/hip_runtime.h>

// Upscaler (W=8, R=4) == exact linear interpolation between block rows:
//   t = 4q + m:  t==0 -> 0;  t in 1..3 -> Z[0];  t>=4 -> (1-m/4)*Z[q-1] + (m/4)*Z[q]
// Shapes fixed by harness: B=4, N=2048, H=1024, S=8192, fp32.
//
// Round-4 lesson: NT stores + 2q/block + XCD swizzle bundle regressed
// (kernel ~68 -> ~79 us). This round: regular stores (L2 write-combining like
// the 6.7 TB/s fill kernel), q-strip of 4 per block with register carry
// (read redundancy 2.0x -> 1.25x), full unroll (5 loads in flight, then 16
// stores), 2048 blocks = full 32-wave/CU residency in one round.

typedef float f4 __attribute__((ext_vector_type(4)));

#define B_DIM 4
#define N_DIM 2048
#define H4    256                    // H=1024 floats -> 256 f4
#define S_DIM 8192
#define LQ    4                      // q's per block
#define NBLK  (B_DIM * (N_DIM / LQ)) // 4 * 512 = 2048 blocks

__global__ __launch_bounds__(256)
void Upscaler_33294586479031_kernel(const f4* __restrict__ Z,
                                    f4* __restrict__ out) {
    const int bid = blockIdx.x;
    const int b   = bid >> 9;            // / 512
    const int qs  = (bid & 511) * LQ;    // first q of the strip
    const int h   = threadIdx.x;         // f4 lane 0..255

    const f4* zbase = Z + (size_t)b * (N_DIM * H4) + h;
    f4* ob = out + (size_t)b * (S_DIM * H4) + (size_t)(4 * qs) * H4 + h;

    if (qs == 0) {
        // Peeled first group: t=0 -> 0, t=1..3 -> Z[0] exactly.
        f4 zp = zbase[0];
        const f4 zero = (f4)(0.0f);
        ob[0 * H4] = zero;
        ob[1 * H4] = zp;
        ob[2 * H4] = zp;
        ob[3 * H4] = zp;
        ob += 4 * H4;
        #pragma unroll
        for (int i = 1; i < LQ; ++i) {
            const f4 zc = zbase[(size_t)i * H4];
            #pragma unroll
            for (int m = 0; m < 4; ++m) {
                const float w1 = 0.25f * (float)m;
                ob[m * H4] = (1.0f - w1) * zp + w1 * zc;
            }
            zp = zc;
            ob += 4 * H4;
        }
    } else {
        f4 zp = zbase[(size_t)(qs - 1) * H4];
        #pragma unroll
        for (int i = 0; i < LQ; ++i) {
            const f4 zc = zbase[(size_t)(qs + i) * H4];
            #pragma unroll
            for (int m = 0; m < 4; ++m) {
                const float w1 = 0.25f * (float)m;
                ob[m * H4] = (1.0f - w1) * zp + w1 * zc;
            }
            zp = zc;
            ob += 4 * H4;
        }
    }
}

extern "C" void kernel_launch(void* const* d_in, const int* in_sizes, int n_in,
                              void* d_out, int out_size, void* d_ws, size_t ws_size,
                              hipStream_t stream) {
    const f4* Z = (const f4*)d_in[0];
    f4* out     = (f4*)d_out;

    Upscaler_33294586479031_kernel<<<NBLK, 256, 0, stream>>>(Z, out);
}